// Round 1
// baseline (152.410 us; speedup 1.0000x reference)
//
#include <hip/hip_runtime.h>

#define NPOS 32768   // 32 * 32 * 32 positions
#define DDIM 256
#define KCODES 1024

typedef __attribute__((ext_vector_type(8))) short bf16x8;
typedef __attribute__((ext_vector_type(4))) float f32x4;
typedef unsigned long long u64;

// ---- fp32 ops with anti-contraction barriers (replicate numpy rounding) ----
__device__ __forceinline__ float sqr_rn(float x) {
    float r = x * x;
    asm volatile("" : "+v"(r));
    return r;
}
__device__ __forceinline__ float add_rn(float a, float b) {
    float r = a + b;
    asm volatile("" : "+v"(r));
    return r;
}

// fp32 -> bf16 round-to-nearest-even (verbatim from verified kernel)
__device__ __forceinline__ unsigned short f2bf(float x) {
    unsigned u = __float_as_uint(x);
    return (unsigned short)((u + 0x7fffu + ((u >> 16) & 1u)) >> 16);
}

// monotone pack: float score -> order-preserving u32, | code in low bits
__device__ __forceinline__ u64 packm(float s, int code) {
    unsigned b = __float_as_uint(s);
    unsigned mm = ((unsigned)((int)b >> 31)) | 0x80000000u;
    return ((u64)(b ^ mm) << 32) | (unsigned)code;
}

// ---------------- wprep: wsq + W bf16 tiled (verbatim from verified prep) ----------------
__global__ __launch_bounds__(256) void wprep(const float* __restrict__ W,
                                             float* __restrict__ wsq,
                                             unsigned short* __restrict__ wb16t) {
    const int t   = threadIdx.x;
    const int bid = blockIdx.x;
    const int row = bid * 16 + (t >> 4);
    const int j   = t & 15;
    const float* base = W + row * DDIM + (j & 7) + (j >> 3) * 128;
    float r = sqr_rn(base[0]);
#pragma unroll
    for (int i = 1; i < 16; ++i) r = add_rn(r, sqr_rn(base[i * 8]));
#pragma unroll
    for (int m = 1; m <= 8; m <<= 1) r = add_rn(r, __shfl_xor(r, m));
    if (j == 0) wsq[row] = r;
#pragma unroll
    for (int jj = 0; jj < 2; ++jj) {
        const int u  = t + jj * 256;      // 512 units = 16 rows x 32 k8
        const int n  = bid * 16 + (u >> 5);
        const int k8 = u & 31;
        const float4 f0 = *(const float4*)&W[n * DDIM + k8 * 8];
        const float4 f1 = *(const float4*)&W[n * DDIM + k8 * 8 + 4];
        bf16x8 o;
        o[0] = (short)f2bf(f0.x); o[1] = (short)f2bf(f0.y);
        o[2] = (short)f2bf(f0.z); o[3] = (short)f2bf(f0.w);
        o[4] = (short)f2bf(f1.x); o[5] = (short)f2bf(f1.y);
        o[6] = (short)f2bf(f1.z); o[7] = (short)f2bf(f1.w);
        const int kk = k8 >> 2, kq = k8 & 3;
        *(bf16x8*)&wb16t[(n >> 8) * 65536 + kk * 8192 + kq * 2048 + (n & 255) * 8] = o;
    }
}

// ---------------- fused: z->bf16 LDS stage + MFMA GEMM + top-2 + exact rescore ----------------
// Grid 512: one block per 64 positions. 256 threads (4 waves), 2 blocks/CU.
// Phase A: stage z slice [64 pos x 256 d] as bf16 A-tile in LDS (layout identical
//          to the verified zb16t tiling -> bit-identical MFMA inputs).
// Phase B: 4 n-panels of 256 codes; B-frags from L2-hot wb16t (reg prefetch);
//          exact top-2 per (row, panel) via sorted-pair shfl tournament -> candL (LDS).
// Phase C: numpy-bit-exact rescore of the 8 candidates (verbatim arithmetic),
//          fp32 z rows re-read from global (L3-hot) into LDS union with the A-tile.
#define ZS 260   // floats per Zs row (bank-spread, as verified)
__global__ __launch_bounds__(256) __attribute__((amdgpu_waves_per_eu(2, 2)))
void vq_fused(const float* __restrict__ z,
              const float* __restrict__ W,
              const float* __restrict__ wsq,
              const unsigned short* __restrict__ wb16t,
              int* __restrict__ out) {
    union Sm {
        unsigned short At[16384];   // 32 KB bf16 A-tile [k8(32)][m(64)][e(8)]
        float          Zs[32 * ZS]; // 33.3 KB fp32 rescore tile (Phase C only)
    };
    __shared__ Sm  sm;
    __shared__ u64 redL[64 * 8];    // 4 KB: [row][quadrant][2]
    __shared__ u64 candL[64 * 8];   // 4 KB: [row][8 candidates]

    const int t   = threadIdx.x;
    const int bid = blockIdx.x;
    const int img = bid >> 4;           // 16 blocks per image
    const int p0  = (bid & 15) * 64;    // first position within image

    // ---- Phase A: z -> bf16 A-tile in LDS ----
    {
        const float* zbase = z + img * (DDIM * 1024) + p0;
#pragma unroll
        for (int jj = 0; jj < 8; ++jj) {
            const int u_ = t + jj * 256;     // 2048 units = 64 m x 32 k8
            const int m  = u_ & 63;
            const int k8 = u_ >> 6;
            const float* src = zbase + k8 * 8192 + m;   // d = k8*8+e, stride 1024 floats
            bf16x8 o;
#pragma unroll
            for (int e = 0; e < 8; ++e) o[e] = (short)f2bf(src[e * 1024]);
            *(bf16x8*)&sm.At[k8 * 512 + m * 8] = o;     // byte addr k8*1024 + m*16
        }
    }
    __syncthreads();

    // ---- Phase B: GEMM over 4 n-panels + exact per-panel top-2 ----
    const int w  = t >> 6;          // wave = col quadrant 0..3
    const int l  = t & 63;
    const int ln = l & 15;
    const int q  = l >> 4;
    const int nw = w * 64;

    const char* aBase = (const char*)sm.At + q * 1024 + ln * 16;
    const char* bBase = (const char*)wb16t + q * 4096 + (nw + ln) * 16;

#pragma unroll 1
    for (int nblk = 0; nblk < 4; ++nblk) {
        const int n0 = nblk * 256;
        float wq[4];
#pragma unroll
        for (int nf = 0; nf < 4; ++nf) wq[nf] = wsq[n0 + nw + nf * 16 + ln];

        f32x4 acc[4][4];
#pragma unroll
        for (int a = 0; a < 4; ++a)
#pragma unroll
            for (int b = 0; b < 4; ++b) acc[a][b] = (f32x4)(0.f);

        const char* bP = bBase + nblk * 131072;
        bf16x8 bfr[4], bnx[4];
#pragma unroll
        for (int nf = 0; nf < 4; ++nf) bfr[nf] = *(const bf16x8*)(bP + nf * 256);

#pragma unroll 1
        for (int kk = 0; kk < 8; ++kk) {
            if (kk < 7) {
#pragma unroll
                for (int nf = 0; nf < 4; ++nf)
                    bnx[nf] = *(const bf16x8*)(bP + (kk + 1) * 16384 + nf * 256);
            }
            bf16x8 afr[4];
#pragma unroll
            for (int mf = 0; mf < 4; ++mf)
                afr[mf] = *(const bf16x8*)(aBase + kk * 4096 + mf * 256);
#pragma unroll
            for (int nf = 0; nf < 4; ++nf)
#pragma unroll
                for (int mf = 0; mf < 4; ++mf)
                    acc[mf][nf] = __builtin_amdgcn_mfma_f32_16x16x32_bf16(
                        afr[mf], bfr[nf], acc[mf][nf], 0, 0, 0);
#pragma unroll
            for (int nf = 0; nf < 4; ++nf) bfr[nf] = bnx[nf];
        }

        // epilogue: score = wsq - 2*acc (row-const zsq dropped), exact top-2/panel
#pragma unroll
        for (int mf = 0; mf < 4; ++mf) {
#pragma unroll
            for (int reg = 0; reg < 4; ++reg) {
                const int row = mf * 16 + q * 4 + reg;
                float s0 = 1e30f, s1 = 1e30f;
                int   i0 = 0,     i1 = 0;
#pragma unroll
                for (int nf = 0; nf < 4; ++nf) {
                    const float s  = fmaf(-2.f, acc[mf][nf][reg], wq[nf]);
                    const int   cc = n0 + nw + nf * 16 + ln;
                    if (s < s0)      { s1 = s0; i1 = i0; s0 = s; i0 = cc; }
                    else if (s < s1) { s1 = s; i1 = cc; }
                }
                u64 c0 = packm(s0, i0), c1 = packm(s1, i1);
                // sorted-pair tournament across the 16-lane ln group
#pragma unroll
                for (int m = 1; m <= 8; m <<= 1) {
                    const u64 o0 = __shfl_xor(c0, m);
                    const u64 o1 = __shfl_xor(c1, m);
                    const u64 hi = (c0 < o0) ? o0 : c0;
                    c0 = (c0 < o0) ? c0 : o0;
                    const u64 lo = (c1 < o1) ? c1 : o1;
                    c1 = (hi < lo) ? hi : lo;
                }
                if (ln == 0) {
                    redL[row * 8 + w * 2]     = c0;
                    redL[row * 8 + w * 2 + 1] = c1;
                }
            }
        }
        __syncthreads();
        if (t < 64) {   // merge 4 quadrant top-2s -> panel top-2
            u64 c0 = ~0ull, c1 = ~0ull;
#pragma unroll
            for (int jj = 0; jj < 8; ++jj) {
                const u64 v = redL[t * 8 + jj];
                if (v < c0)      { c1 = c0; c0 = v; }
                else if (v < c1) { c1 = v; }
            }
            candL[t * 8 + nblk * 2]     = c0;
            candL[t * 8 + nblk * 2 + 1] = c1;
        }
        __syncthreads();   // protects redL reuse + publishes candL
    }

    // ---- Phase C: exact numpy-bit rescore (verbatim arithmetic), 2 chunks of 32 pos ----
    const float* zimg = z + img * (DDIM * 1024) + p0;
#pragma unroll 1
    for (int c = 0; c < 2; ++c) {
#pragma unroll
        for (int jj = 0; jj < 8; ++jj) {
            const int f4 = t + jj * 256;
            const int d = f4 >> 3, p4 = f4 & 7;
            const float4 v = *(const float4*)&zimg[d * 1024 + c * 32 + p4 * 4];
            sm.Zs[(p4 * 4 + 0) * ZS + d] = v.x;
            sm.Zs[(p4 * 4 + 1) * ZS + d] = v.y;
            sm.Zs[(p4 * 4 + 2) * ZS + d] = v.z;
            sm.Zs[(p4 * 4 + 3) * ZS + d] = v.w;
        }
        __syncthreads();
        const int pl = t >> 3, slot = t & 7;
        const float* zr = &sm.Zs[pl * ZS];

        // numpy-exact zsq: slot chains + xor butterfly, halves joined last
        float h0 = sqr_rn(zr[slot]);
        float h1 = sqr_rn(zr[128 + slot]);
#pragma unroll
        for (int i = 1; i < 16; ++i) {
            h0 = add_rn(h0, sqr_rn(zr[slot + 8 * i]));
            h1 = add_rn(h1, sqr_rn(zr[128 + slot + 8 * i]));
        }
#pragma unroll
        for (int m = 1; m <= 4; m <<= 1) {
            h0 = add_rn(h0, __shfl_xor(h0, m));
            h1 = add_rn(h1, __shfl_xor(h1, m));
        }
        const float zq = add_rn(h0, h1);

        const int code = (int)(unsigned)(candL[(c * 32 + pl) * 8 + slot] & 0xffffffffULL);
        const float* wr = W + code * DDIM;
        // sequential fma chain over d ascending — bit-identical to verified path
        float M = 0.f;
#pragma unroll 8
        for (int d4 = 0; d4 < 64; ++d4) {
            const float4 zv = *(const float4*)&zr[d4 * 4];
            const float4 wv = *(const float4*)&wr[d4 * 4];
            M = fmaf(zv.x, wv.x, M);
            M = fmaf(zv.y, wv.y, M);
            M = fmaf(zv.z, wv.z, M);
            M = fmaf(zv.w, wv.w, M);
        }
        const float s = add_rn(fmaf(-2.f, M, zq), wsq[code]);
        u64 v = ((u64)__float_as_uint(s) << 32) | (unsigned)code;
#pragma unroll
        for (int m = 1; m <= 4; m <<= 1) {
            const u64 o = __shfl_xor(v, m);
            if (o < v) v = o;
        }
        if (slot == 0) out[img * 1024 + p0 + c * 32 + pl] = (int)(unsigned)(v & 0xffffffffULL);
        __syncthreads();   // protect Zs reuse for next chunk
    }
}

extern "C" void kernel_launch(void* const* d_in, const int* in_sizes, int n_in,
                              void* d_out, int out_size, void* d_ws, size_t ws_size,
                              hipStream_t stream) {
    const float* z = (const float*)d_in[0];   // [32, 256, 32, 32] NCHW
    const float* W = (const float*)d_in[1];   // [1024, 256]
    int* out = (int*)d_out;                   // [32768] int32 indices

    char* ws = (char*)d_ws;
    float*          wsq   = (float*)ws;                  //   4 KB @ 0
    unsigned short* wb16t = (unsigned short*)(ws + 4096); // 512 KB

    wprep<<<KCODES / 16, 256, 0, stream>>>(W, wsq, wb16t);
    vq_fused<<<NPOS / 64, 256, 0, stream>>>(z, W, wsq, wb16t, out);
}

// Round 3
// 144.478 us; speedup vs baseline: 1.0549x; 1.0549x over previous
//
#include <hip/hip_runtime.h>

#define NPOS 32768   // 32 * 32 * 32 positions
#define DDIM 256
#define KCODES 1024

typedef __attribute__((ext_vector_type(8))) short bf16x8;
typedef __attribute__((ext_vector_type(4))) float f32x4;
typedef unsigned long long u64;

// ---- fp32 ops with anti-contraction barriers (replicate numpy rounding) ----
__device__ __forceinline__ float sqr_rn(float x) {
    float r = x * x;
    asm volatile("" : "+v"(r));
    return r;
}
__device__ __forceinline__ float add_rn(float a, float b) {
    float r = a + b;
    asm volatile("" : "+v"(r));
    return r;
}

// fp32 -> bf16 round-to-nearest-even (verbatim from verified kernel)
__device__ __forceinline__ unsigned short f2bf(float x) {
    unsigned u = __float_as_uint(x);
    return (unsigned short)((u + 0x7fffu + ((u >> 16) & 1u)) >> 16);
}

// monotone pack: float score -> order-preserving u32, | code in low bits
__device__ __forceinline__ u64 packm(float s, int code) {
    unsigned b = __float_as_uint(s);
    unsigned mm = ((unsigned)((int)b >> 31)) | 0x80000000u;
    return ((u64)(b ^ mm) << 32) | (unsigned)code;
}

// ---------------- wprep: wsq + W bf16 tiled (verbatim from verified prep) ----------------
__global__ __launch_bounds__(256) void wprep(const float* __restrict__ W,
                                             float* __restrict__ wsq,
                                             unsigned short* __restrict__ wb16t) {
    const int t   = threadIdx.x;
    const int bid = blockIdx.x;
    const int row = bid * 16 + (t >> 4);
    const int j   = t & 15;
    const float* base = W + row * DDIM + (j & 7) + (j >> 3) * 128;
    float r = sqr_rn(base[0]);
#pragma unroll
    for (int i = 1; i < 16; ++i) r = add_rn(r, sqr_rn(base[i * 8]));
#pragma unroll
    for (int m = 1; m <= 8; m <<= 1) r = add_rn(r, __shfl_xor(r, m));
    if (j == 0) wsq[row] = r;
#pragma unroll
    for (int jj = 0; jj < 2; ++jj) {
        const int u  = t + jj * 256;      // 512 units = 16 rows x 32 k8
        const int n  = bid * 16 + (u >> 5);
        const int k8 = u & 31;
        const float4 f0 = *(const float4*)&W[n * DDIM + k8 * 8];
        const float4 f1 = *(const float4*)&W[n * DDIM + k8 * 8 + 4];
        bf16x8 o;
        o[0] = (short)f2bf(f0.x); o[1] = (short)f2bf(f0.y);
        o[2] = (short)f2bf(f0.z); o[3] = (short)f2bf(f0.w);
        o[4] = (short)f2bf(f1.x); o[5] = (short)f2bf(f1.y);
        o[6] = (short)f2bf(f1.z); o[7] = (short)f2bf(f1.w);
        const int kk = k8 >> 2, kq = k8 & 3;
        *(bf16x8*)&wb16t[(n >> 8) * 65536 + kk * 8192 + kq * 2048 + (n & 255) * 8] = o;
    }
}

// ---------------- fused: z->bf16 LDS stage + MFMA GEMM + top-2 + exact rescore ----------------
// Grid 1024: one block per 32 positions, 256 threads (4 waves).
// LDS 37.4 KB -> 4 blocks/CU resident; staggered blocks overlap phases
// (one block's MFMA hides another's stage/gather latency).
// Phase A: stage z slice [32 pos x 256 d] as bf16 A-tile in LDS (same tiling
//          and f2bf as verified -> bit-identical MFMA inputs).
// Phase B: 4 n-panels of 256 codes; B-frags from L2-hot wb16t (reg prefetch);
//          exact top-2 per (row, panel) via sorted-pair shfl tournament -> candL.
// Phase C: numpy-bit-exact rescore of the 8 candidates (verbatim arithmetic),
//          fp32 z rows re-read from global (L3-hot) into LDS union with A-tile.
#define ZS 260   // floats per Zs row (bank-spread, as verified)
__global__ __launch_bounds__(256)
void vq_fused(const float* __restrict__ z,
              const float* __restrict__ W,
              const float* __restrict__ wsq,
              const unsigned short* __restrict__ wb16t,
              int* __restrict__ out) {
    union Sm {
        unsigned short At[8192];    // 16 KB bf16 A-tile [k8(32)][m(32)][e(8)]
        float          Zs[32 * ZS]; // 33.3 KB fp32 rescore tile (Phase C only)
    };
    __shared__ Sm  sm;
    __shared__ u64 redL[32 * 8];    // 2 KB: [row][quadrant][2]
    __shared__ u64 candL[32 * 8];   // 2 KB: [row][8 candidates]

    const int t   = threadIdx.x;
    const int bid = blockIdx.x;
    const int img = bid >> 5;           // 32 blocks per image
    const int p0  = (bid & 31) * 32;    // first position within image

    // ---- Phase A: z -> bf16 A-tile in LDS ----
    {
        const float* zbase = z + img * (DDIM * 1024) + p0;
#pragma unroll
        for (int jj = 0; jj < 4; ++jj) {
            const int u_ = t + jj * 256;     // 1024 units = 32 m x 32 k8
            const int m  = u_ & 31;
            const int k8 = u_ >> 5;
            const float* src = zbase + k8 * 8192 + m;   // d = k8*8+e, stride 1024 floats
            bf16x8 o;
#pragma unroll
            for (int e = 0; e < 8; ++e) o[e] = (short)f2bf(src[e * 1024]);
            *(bf16x8*)&sm.At[k8 * 256 + m * 8] = o;     // byte addr k8*512 + m*16
        }
    }
    __syncthreads();

    // ---- Phase B: GEMM over 4 n-panels + exact per-panel top-2 ----
    const int w  = t >> 6;          // wave = col quadrant 0..3
    const int l  = t & 63;
    const int ln = l & 15;
    const int q  = l >> 4;
    const int nw = w * 64;

    const char* aBase = (const char*)sm.At + q * 512 + ln * 16;
    const char* bBase = (const char*)wb16t + q * 4096 + (nw + ln) * 16;

#pragma unroll 1
    for (int nblk = 0; nblk < 4; ++nblk) {
        const int n0 = nblk * 256;
        float wq[4];
#pragma unroll
        for (int nf = 0; nf < 4; ++nf) wq[nf] = wsq[n0 + nw + nf * 16 + ln];

        f32x4 acc[2][4];
#pragma unroll
        for (int a = 0; a < 2; ++a)
#pragma unroll
            for (int b = 0; b < 4; ++b) acc[a][b] = (f32x4)(0.f);

        const char* bP = bBase + nblk * 131072;
        bf16x8 bfr[4], bnx[4];
#pragma unroll
        for (int nf = 0; nf < 4; ++nf) bfr[nf] = *(const bf16x8*)(bP + nf * 256);

#pragma unroll 1
        for (int kk = 0; kk < 8; ++kk) {
            if (kk < 7) {
#pragma unroll
                for (int nf = 0; nf < 4; ++nf)
                    bnx[nf] = *(const bf16x8*)(bP + (kk + 1) * 16384 + nf * 256);
            }
            bf16x8 afr[2];
#pragma unroll
            for (int mf = 0; mf < 2; ++mf)
                afr[mf] = *(const bf16x8*)(aBase + kk * 2048 + mf * 256);
#pragma unroll
            for (int nf = 0; nf < 4; ++nf)
#pragma unroll
                for (int mf = 0; mf < 2; ++mf)
                    acc[mf][nf] = __builtin_amdgcn_mfma_f32_16x16x32_bf16(
                        afr[mf], bfr[nf], acc[mf][nf], 0, 0, 0);
#pragma unroll
            for (int nf = 0; nf < 4; ++nf) bfr[nf] = bnx[nf];
        }

        // epilogue: score = wsq - 2*acc (row-const zsq dropped), exact top-2/panel
#pragma unroll
        for (int mf = 0; mf < 2; ++mf) {
#pragma unroll
            for (int reg = 0; reg < 4; ++reg) {
                const int row = mf * 16 + q * 4 + reg;
                float s0 = 1e30f, s1 = 1e30f;
                int   i0 = 0,     i1 = 0;
#pragma unroll
                for (int nf = 0; nf < 4; ++nf) {
                    const float s  = fmaf(-2.f, acc[mf][nf][reg], wq[nf]);
                    const int   cc = n0 + nw + nf * 16 + ln;
                    if (s < s0)      { s1 = s0; i1 = i0; s0 = s; i0 = cc; }
                    else if (s < s1) { s1 = s; i1 = cc; }
                }
                u64 c0 = packm(s0, i0), c1 = packm(s1, i1);
                // sorted-pair tournament across the 16-lane ln group
#pragma unroll
                for (int m = 1; m <= 8; m <<= 1) {
                    const u64 o0 = __shfl_xor(c0, m);
                    const u64 o1 = __shfl_xor(c1, m);
                    const u64 hi = (c0 < o0) ? o0 : c0;
                    c0 = (c0 < o0) ? c0 : o0;
                    const u64 lo = (c1 < o1) ? c1 : o1;
                    c1 = (hi < lo) ? hi : lo;
                }
                if (ln == 0) {
                    redL[row * 8 + w * 2]     = c0;
                    redL[row * 8 + w * 2 + 1] = c1;
                }
            }
        }
        __syncthreads();
        if (t < 32) {   // merge 4 quadrant top-2s -> panel top-2
            u64 c0 = ~0ull, c1 = ~0ull;
#pragma unroll
            for (int jj = 0; jj < 8; ++jj) {
                const u64 v = redL[t * 8 + jj];
                if (v < c0)      { c1 = c0; c0 = v; }
                else if (v < c1) { c1 = v; }
            }
            candL[t * 8 + nblk * 2]     = c0;
            candL[t * 8 + nblk * 2 + 1] = c1;
        }
        __syncthreads();   // protects redL reuse + publishes candL
    }

    // ---- Phase C: exact numpy-bit rescore (verbatim arithmetic), 32 positions ----
    const float* zimg = z + img * (DDIM * 1024) + p0;
#pragma unroll
    for (int jj = 0; jj < 8; ++jj) {
        const int f4 = t + jj * 256;
        const int d = f4 >> 3, p4 = f4 & 7;
        const float4 v = *(const float4*)&zimg[d * 1024 + p4 * 4];
        sm.Zs[(p4 * 4 + 0) * ZS + d] = v.x;
        sm.Zs[(p4 * 4 + 1) * ZS + d] = v.y;
        sm.Zs[(p4 * 4 + 2) * ZS + d] = v.z;
        sm.Zs[(p4 * 4 + 3) * ZS + d] = v.w;
    }
    __syncthreads();
    {
        const int pl = t >> 3, slot = t & 7;
        const float* zr = &sm.Zs[pl * ZS];

        // numpy-exact zsq: slot chains + xor butterfly, halves joined last
        float h0 = sqr_rn(zr[slot]);
        float h1 = sqr_rn(zr[128 + slot]);
#pragma unroll
        for (int i = 1; i < 16; ++i) {
            h0 = add_rn(h0, sqr_rn(zr[slot + 8 * i]));
            h1 = add_rn(h1, sqr_rn(zr[128 + slot + 8 * i]));
        }
#pragma unroll
        for (int m = 1; m <= 4; m <<= 1) {
            h0 = add_rn(h0, __shfl_xor(h0, m));
            h1 = add_rn(h1, __shfl_xor(h1, m));
        }
        const float zq = add_rn(h0, h1);

        const int code = (int)(unsigned)(candL[pl * 8 + slot] & 0xffffffffULL);
        const float* wr = W + code * DDIM;
        // sequential fma chain over d ascending — bit-identical to verified path
        float M = 0.f;
#pragma unroll 8
        for (int d4 = 0; d4 < 64; ++d4) {
            const float4 zv = *(const float4*)&zr[d4 * 4];
            const float4 wv = *(const float4*)&wr[d4 * 4];
            M = fmaf(zv.x, wv.x, M);
            M = fmaf(zv.y, wv.y, M);
            M = fmaf(zv.z, wv.z, M);
            M = fmaf(zv.w, wv.w, M);
        }
        const float s = add_rn(fmaf(-2.f, M, zq), wsq[code]);
        u64 v = ((u64)__float_as_uint(s) << 32) | (unsigned)code;
#pragma unroll
        for (int m = 1; m <= 4; m <<= 1) {
            const u64 o = __shfl_xor(v, m);
            if (o < v) v = o;
        }
        if (slot == 0) out[img * 1024 + p0 + pl] = (int)(unsigned)(v & 0xffffffffULL);
    }
}

extern "C" void kernel_launch(void* const* d_in, const int* in_sizes, int n_in,
                              void* d_out, int out_size, void* d_ws, size_t ws_size,
                              hipStream_t stream) {
    const float* z = (const float*)d_in[0];   // [32, 256, 32, 32] NCHW
    const float* W = (const float*)d_in[1];   // [1024, 256]
    int* out = (int*)d_out;                   // [32768] int32 indices

    char* ws = (char*)d_ws;
    float*          wsq   = (float*)ws;                  //   4 KB @ 0
    unsigned short* wb16t = (unsigned short*)(ws + 4096); // 512 KB

    wprep<<<KCODES / 16, 256, 0, stream>>>(W, wsq, wb16t);
    vq_fused<<<NPOS / 32, 256, 0, stream>>>(z, W, wsq, wb16t, out);
}